// Round 1
// baseline (1392.401 us; speedup 1.0000x reference)
//
#include <hip/hip_runtime.h>

// MD-GRU (4-direction 2D GRU) on MI355X.
// Wavefront over 63 anti-diagonals; per cell: [h_top;h_left](128x256) @ [U1;U2](256x384)
// via v_mfma_f32_16x16x32_bf16, f32 elementwise GRU epilogue.
// Workspace layout (bytes):
//   [0, 786432)                      : U^T bf16, [a][n(384)][k(256)]  (k<128 -> U1[k][n], k>=128 -> U2[k-128][n])
//   [786432, +4MB)                   : h bf16 slot0  [a][i(32)][b(128)][hh(128)]
//   [786432+4MB, +4MB)               : h bf16 slot1
//   [786432+8MB, +8MB)               : h f32  slot0
//   [786432+16MB, +8MB)              : h f32  slot1
// Total ~25.95 MB.

#define B_ 128
#define N_ 32
#define H_ 128
#define TH 384
#define KK 256

typedef short bf16x8 __attribute__((ext_vector_type(8)));
typedef float f32x4 __attribute__((ext_vector_type(4)));

__device__ inline ushort f2bf(float f) {
    unsigned u = __float_as_uint(f);
    unsigned r = (u + 0x7FFFu + ((u >> 16) & 1u)) >> 16;  // RNE
    return (ushort)r;
}
__device__ inline float fsig(float x) { return 1.0f / (1.0f + __expf(-x)); }
__device__ inline float ftanh(float x) {
    float ax = fabsf(x);
    float t = __expf(-2.0f * ax);
    float r = (1.0f - t) / (1.0f + t);
    return copysignf(r, x);
}

// ---- U1,U2 (f32, [a][k][n]) -> U^T bf16 [a][n][kk] with kk = mat*128 + k ----
__global__ void conv_u(const float* __restrict__ U1, const float* __restrict__ U2,
                       ushort* __restrict__ ubf) {
    __shared__ float t[32][33];
    int bx = blockIdx.x;
    int amat = bx / 48, tile = bx % 48;
    int kt = tile / 12, ntl = tile % 12;
    int a = amat >> 1, mat = amat & 1;
    int kk0 = kt * 32, n0 = ntl * 32;
    int tx = threadIdx.x, ty = threadIdx.y;
    const float* U = mat ? U2 : U1;
#pragma unroll
    for (int r = 0; r < 4; r++)
        t[ty + r * 8][tx] = U[(a * H_ + kk0 + ty + r * 8) * TH + n0 + tx];
    __syncthreads();
#pragma unroll
    for (int r = 0; r < 4; r++) {
        int n = n0 + ty + r * 8;
        int kkl = kk0 + tx;
        ubf[(a * TH + n) * KK + mat * H_ + kkl] = f2bf(t[tx][ty + r * 8]);
    }
}

// ---- one anti-diagonal step ----
__global__ __launch_bounds__(256) void diag_step(
    const float* __restrict__ x, const float* __restrict__ Wx,
    const float* __restrict__ bvec, const ushort* __restrict__ ubf,
    const ushort* __restrict__ hbf_prev, ushort* __restrict__ hbf_cur,
    const float* __restrict__ hf_prev, float* __restrict__ hf_cur,
    int d, int ilo, int w) {
    int bx = blockIdx.x;
    int per_dir = w * 2;
    int a = bx / per_dir;
    int r0 = bx % per_dir;
    int ci = r0 >> 1, half = r0 & 1;
    int i = ilo + ci, j = d - i;

    int tid = threadIdx.x;
    int lane = tid & 63, wave = tid >> 6;
    int wm = wave >> 1, wn = wave & 1;  // 2x2 wave grid: M halves x col halves
    int l16 = lane & 15, lg = lane >> 4;

    const ushort* htop_bf = (i >= 1) ? hbf_prev + (a * N_ + (i - 1)) * (B_ * H_) : nullptr;
    const ushort* hleft_bf = (j >= 1) ? hbf_prev + (a * N_ + i) * (B_ * H_) : nullptr;
    const float* htop_f = (i >= 1) ? hf_prev + (a * N_ + (i - 1)) * (B_ * H_) : nullptr;
    const float* hleft_f = (j >= 1) ? hf_prev + (a * N_ + i) * (B_ * H_) : nullptr;

    f32x4 acc[4][3][2];
#pragma unroll
    for (int mt = 0; mt < 4; mt++)
#pragma unroll
        for (int p = 0; p < 3; p++)
#pragma unroll
            for (int nt = 0; nt < 2; nt++)
                acc[mt][p][nt] = (f32x4){0.0f, 0.0f, 0.0f, 0.0f};

    const ushort* ub = ubf + a * (TH * KK);

    // h_top @ U1 : K-steps 0..3 (kk in [0,128))
    if (htop_bf) {
#pragma unroll
        for (int ks = 0; ks < 4; ks++) {
            int koff = ks * 32 + lg * 8;
            bf16x8 af[4];
#pragma unroll
            for (int mt = 0; mt < 4; mt++) {
                int row = wm * 64 + mt * 16 + l16;
                af[mt] = *(const bf16x8*)(htop_bf + row * H_ + koff);
            }
#pragma unroll
            for (int p = 0; p < 3; p++)
#pragma unroll
                for (int nt = 0; nt < 2; nt++) {
                    int n = p * H_ + half * 64 + wn * 32 + nt * 16 + l16;
                    bf16x8 bfr = *(const bf16x8*)(ub + n * KK + koff);
#pragma unroll
                    for (int mt = 0; mt < 4; mt++)
                        acc[mt][p][nt] = __builtin_amdgcn_mfma_f32_16x16x32_bf16(
                            af[mt], bfr, acc[mt][p][nt], 0, 0, 0);
                }
        }
    }
    // h_left @ U2 : K-steps 4..7 (kk in [128,256))
    if (hleft_bf) {
#pragma unroll
        for (int ks = 0; ks < 4; ks++) {
            int koff = ks * 32 + lg * 8;
            bf16x8 af[4];
#pragma unroll
            for (int mt = 0; mt < 4; mt++) {
                int row = wm * 64 + mt * 16 + l16;
                af[mt] = *(const bf16x8*)(hleft_bf + row * H_ + koff);
            }
#pragma unroll
            for (int p = 0; p < 3; p++)
#pragma unroll
                for (int nt = 0; nt < 2; nt++) {
                    int n = p * H_ + half * 64 + wn * 32 + nt * 16 + l16;
                    bf16x8 bfr = *(const bf16x8*)(ub + n * KK + H_ + koff);
#pragma unroll
                    for (int mt = 0; mt < 4; mt++)
                        acc[mt][p][nt] = __builtin_amdgcn_mfma_f32_16x16x32_bf16(
                            af[mt], bfr, acc[mt][p][nt], 0, 0, 0);
                }
        }
    }

    // epilogue: r/z/n gates + GRU mix, write f32 + bf16 h
    int ri = (a & 1) ? (N_ - 1 - i) : i;
    int cj = (a & 2) ? (N_ - 1 - j) : j;
    const float* xcol = x + ri * N_ + cj;
    float xv[4][4];
#pragma unroll
    for (int mt = 0; mt < 4; mt++)
#pragma unroll
        for (int r = 0; r < 4; r++) {
            int b = wm * 64 + mt * 16 + lg * 4 + r;
            xv[mt][r] = xcol[b * (N_ * N_)];
        }

    int cello = (a * N_ + i) * (B_ * H_);

#pragma unroll
    for (int nt = 0; nt < 2; nt++) {
        int hh = half * 64 + wn * 32 + nt * 16 + l16;
        float wxr = Wx[a * TH + hh], br = bvec[a * TH + hh];
        float wxz = Wx[a * TH + H_ + hh], bz = bvec[a * TH + H_ + hh];
        float wxn = Wx[a * TH + 2 * H_ + hh], bn = bvec[a * TH + 2 * H_ + hh];
#pragma unroll
        for (int mt = 0; mt < 4; mt++) {
#pragma unroll
            for (int r = 0; r < 4; r++) {
                int b = wm * 64 + mt * 16 + lg * 4 + r;
                float Gr = acc[mt][0][nt][r];
                float Gz = acc[mt][1][nt][r];
                float Gn = acc[mt][2][nt][r];
                float xb = xv[mt][r];
                float rr = fsig(xb * wxr + br + Gr);
                float zz = fsig(xb * wxz + bz + Gz);
                float nn = ftanh(xb * wxn + bn + rr * Gn);
                float ht = htop_f ? htop_f[b * H_ + hh] : 0.0f;
                float hl = hleft_f ? hleft_f[b * H_ + hh] : 0.0f;
                float h = (1.0f - zz) * nn + zz * 0.5f * (ht + hl);
                hf_cur[cello + b * H_ + hh] = h;
                hbf_cur[cello + b * H_ + hh] = f2bf(h);
            }
        }
    }
}

// ---- final: concat 4 terminal h's -> logits -> log_softmax ----
__global__ void classify(const float* __restrict__ hf, const float* __restrict__ Wo,
                         const float* __restrict__ bo, float* __restrict__ out) {
    int b = blockIdx.x;
    int lane = threadIdx.x;  // 64
    float acc[10];
#pragma unroll
    for (int o = 0; o < 10; o++) acc[o] = 0.0f;
#pragma unroll
    for (int kkx = 0; kkx < 8; kkx++) {
        int k = kkx * 64 + lane;
        int a = k >> 7, hh = k & 127;
        float fh = hf[(a * N_ + (N_ - 1)) * (B_ * H_) + b * H_ + hh];
#pragma unroll
        for (int o = 0; o < 10; o++) acc[o] += fh * Wo[k * 10 + o];
    }
    float logits[10];
#pragma unroll
    for (int o = 0; o < 10; o++) {
        float v = acc[o];
#pragma unroll
        for (int off = 32; off; off >>= 1) v += __shfl_xor(v, off, 64);
        logits[o] = v + bo[o];
    }
    float m = logits[0];
#pragma unroll
    for (int o = 1; o < 10; o++) m = fmaxf(m, logits[o]);
    float s = 0.0f;
#pragma unroll
    for (int o = 0; o < 10; o++) s += __expf(logits[o] - m);
    float lse = m + __logf(s);
    if (lane == 0) {
#pragma unroll
        for (int o = 0; o < 10; o++) out[b * 10 + o] = logits[o] - lse;
    }
}

extern "C" void kernel_launch(void* const* d_in, const int* in_sizes, int n_in,
                              void* d_out, int out_size, void* d_ws, size_t ws_size,
                              hipStream_t stream) {
    const float* x = (const float*)d_in[0];
    const float* Wx = (const float*)d_in[1];
    const float* U1 = (const float*)d_in[2];
    const float* U2 = (const float*)d_in[3];
    const float* bv = (const float*)d_in[4];
    const float* Wo = (const float*)d_in[5];
    const float* bo = (const float*)d_in[6];
    float* out = (float*)d_out;

    char* ws = (char*)d_ws;
    ushort* ubf = (ushort*)ws;                                    // 786432 B
    ushort* hbf0 = (ushort*)(ws + 786432);                        // 4 MB
    ushort* hbf1 = (ushort*)(ws + 786432 + 4194304);              // 4 MB
    float* hf0 = (float*)(ws + 786432 + 8388608);                 // 8 MB
    float* hf1 = (float*)(ws + 786432 + 8388608 + 8388608);       // 8 MB

    hipLaunchKernelGGL(conv_u, dim3(384), dim3(32, 8), 0, stream, U1, U2, ubf);

    for (int d = 0; d < 63; d++) {
        int ilo = (d - 31 > 0) ? (d - 31) : 0;
        int ihi = (d < 31) ? d : 31;
        int w = ihi - ilo + 1;
        int cur = d & 1;
        ushort* hbc = cur ? hbf1 : hbf0;
        const ushort* hbp = cur ? hbf0 : hbf1;
        float* hfc = cur ? hf1 : hf0;
        const float* hfp = cur ? hf0 : hf1;
        hipLaunchKernelGGL(diag_step, dim3(4 * w * 2), dim3(256), 0, stream,
                           x, Wx, bv, ubf, hbp, hbc, hfp, hfc, d, ilo, w);
    }
    // d=62 wrote slot 0
    hipLaunchKernelGGL(classify, dim3(128), dim3(64), 0, stream, hf0, Wo, bo, out);
}

// Round 2
// 429.805 us; speedup vs baseline: 3.2396x; 3.2396x over previous
//
#include <hip/hip_runtime.h>

// MD-GRU (4-direction 2D GRU), block-resident wavefront scan.
// 256 blocks = 4 dirs x 64 batch-pairs; each block runs the entire 63-step
// diagonal recurrence with h state in LDS and U^T persistent in registers.
// Workspace: [0,786432) U^T bf16 [a][n(384)][kk(256)]; [786432,+256KB) finals f32 [a][b][hh].

#define B_ 128
#define N_ 32
#define H_ 128
#define TH 384
#define KK 256

typedef short bf16x8 __attribute__((ext_vector_type(8)));
typedef float f32x4 __attribute__((ext_vector_type(4)));

__device__ inline ushort f2bf(float f) {
    unsigned u = __float_as_uint(f);
    return (ushort)((u + 0x7FFFu + ((u >> 16) & 1u)) >> 16);  // RNE
}
__device__ inline float fsig(float x) { return 1.0f / (1.0f + __expf(-x)); }
__device__ inline float ftanh(float x) {
    float ax = fabsf(x);
    float t = __expf(-2.0f * ax);
    float r = (1.0f - t) / (1.0f + t);
    return copysignf(r, x);
}

// ---- U1,U2 (f32, [a][k][n]) -> U^T bf16 [a][n][kk], kk = mat*128 + k ----
__global__ void conv_u(const float* __restrict__ U1, const float* __restrict__ U2,
                       ushort* __restrict__ ubf) {
    __shared__ float t[32][33];
    int bx = blockIdx.x;
    int amat = bx / 48, tile = bx % 48;
    int kt = tile / 12, ntl = tile % 12;
    int a = amat >> 1, mat = amat & 1;
    int kk0 = kt * 32, n0 = ntl * 32;
    int tx = threadIdx.x, ty = threadIdx.y;
    const float* U = mat ? U2 : U1;
#pragma unroll
    for (int r = 0; r < 4; r++)
        t[ty + r * 8][tx] = U[(a * H_ + kk0 + ty + r * 8) * TH + n0 + tx];
    __syncthreads();
#pragma unroll
    for (int r = 0; r < 4; r++) {
        int n = n0 + ty + r * 8;
        int kkl = kk0 + tx;
        ubf[(a * TH + n) * KK + mat * H_ + kkl] = f2bf(t[tx][ty + r * 8]);
    }
}

// ---- persistent block-resident scan: 256 blocks x 256 threads (4 waves) ----
__global__ __launch_bounds__(256, 1) void scan_all(
    const float* __restrict__ x, const float* __restrict__ Wx,
    const float* __restrict__ bvec, const ushort* __restrict__ ubf,
    float* __restrict__ finals) {

    // LDS: bf16 h single buffer [slot(33)][bl(2)][hh(128)], byte-swizzled;
    //      f32 h double buffer [buf(2)][slot(33)][hh(128)][bl(2)];
    //      x pre-flipped [bl(2)][i*32+j]
    __shared__ ushort hbf[33 * 2 * 128];
    __shared__ float hf[2][33 * 128 * 2];
    __shared__ float xl[2 * 1024];

    int bx = blockIdx.x;
    int a = bx >> 6, chunk = bx & 63;
    int tid = threadIdx.x;
    int lane = tid & 63, wn = tid >> 6;
    int l16 = lane & 15, lg = lane >> 4;

    for (int idx = tid; idx < 33 * 2 * 128; idx += 256) hbf[idx] = 0;
    for (int idx = tid; idx < 2 * 33 * 128 * 2; idx += 256) ((float*)hf)[idx] = 0.0f;
    for (int idx = tid; idx < 2048; idx += 256) {
        int bl = idx >> 10, cell = idx & 1023;
        int i = cell >> 5, j = cell & 31;
        int ri = (a & 1) ? (31 - i) : i;
        int cj = (a & 2) ? (31 - j) : j;
        int b = chunk * 2 + bl;
        xl[idx] = x[(b * N_ + ri) * N_ + cj];
    }

    // persistent B fragments: U^T, 48 frags (192 VGPR bf16)
    const ushort* ub = ubf + a * (TH * KK);
    bf16x8 Bf[3][2][8];
#pragma unroll
    for (int p = 0; p < 3; p++)
#pragma unroll
        for (int nt = 0; nt < 2; nt++) {
            int n = p * H_ + wn * 32 + nt * 16 + l16;
#pragma unroll
            for (int ks = 0; ks < 8; ks++)
                Bf[p][nt][ks] = *(const bf16x8*)(ub + n * KK + ks * 32 + lg * 8);
        }

    float wxs[2][3], bs[2][3];
#pragma unroll
    for (int nt = 0; nt < 2; nt++) {
        int hh = wn * 32 + nt * 16 + l16;
#pragma unroll
        for (int p = 0; p < 3; p++) {
            wxs[nt][p] = Wx[a * TH + p * H_ + hh];
            bs[nt][p] = bvec[a * TH + p * H_ + hh];
        }
    }
    __syncthreads();

    float hreg[4][2][4];  // [mt][nt][r]
#pragma unroll
    for (int mt = 0; mt < 4; mt++)
#pragma unroll
        for (int nt = 0; nt < 2; nt++)
#pragma unroll
            for (int r = 0; r < 4; r++) hreg[mt][nt][r] = 0.0f;

    int ciA = (l16 >> 1);  // + mt*8
    int blA = l16 & 1;

    for (int d = 0; d < 63; d++) {
        int ilo = (d > 31) ? (d - 31) : 0;
        int ihi = (d < 31) ? d : 31;
        int w = ihi - ilo + 1;
        int pb = (d + 1) & 1, cb = d & 1;

        // per-mt A-load bases (lane-local clamped slot indexing)
        int tb[4], txr[4], lb[4], lxr[4];
#pragma unroll
        for (int mt = 0; mt < 4; mt++) {
            int ci = mt * 8 + ciA;
            int i = ilo + ci;
            int ic = (i < ihi) ? i : ihi;
            tb[mt] = ic * 512 + blA * 256;
            txr[mt] = (ic & 7) << 4;
            lb[mt] = (ic + 1) * 512 + blA * 256;
            lxr[mt] = ((ic + 1) & 7) << 4;
        }

        f32x4 acc[4][3][2];
        bf16x8 Af[2][4];
        // prefetch ks=0
#pragma unroll
        for (int mt = 0; mt < 4; mt++) {
            int off = tb[mt] + ((lg * 16) ^ txr[mt]);
            Af[0][mt] = *(const bf16x8*)((const char*)hbf + off);
        }
#pragma unroll
        for (int ks = 0; ks < 8; ks++) {
            if (ks < 7) {
                int ks1 = ks + 1;
#pragma unroll
                for (int mt = 0; mt < 4; mt++) {
                    int base = (ks1 < 4) ? tb[mt] : lb[mt];
                    int sx = (ks1 < 4) ? txr[mt] : lxr[mt];
                    int off = base + ((((ks1 & 3) * 64) + lg * 16) ^ sx);
                    Af[ks1 & 1][mt] = *(const bf16x8*)((const char*)hbf + off);
                }
            }
#pragma unroll
            for (int p = 0; p < 3; p++)
#pragma unroll
                for (int nt = 0; nt < 2; nt++)
#pragma unroll
                    for (int mt = 0; mt < 4; mt++) {
                        f32x4 cin = (ks == 0) ? (f32x4){0.0f, 0.0f, 0.0f, 0.0f}
                                              : acc[mt][p][nt];
                        acc[mt][p][nt] = __builtin_amdgcn_mfma_f32_16x16x32_bf16(
                            Af[ks & 1][mt], Bf[p][nt][ks], cin, 0, 0, 0);
                    }
        }

        // epilogue: gates + GRU mix into hreg (reads prev f32 buf + x)
#pragma unroll
        for (int mt = 0; mt < 4; mt++) {
#pragma unroll
            for (int p2 = 0; p2 < 2; p2++) {
                int ci = mt * 8 + (lg << 1) + p2;
                int i = ilo + ci;
                int ic = (i < ihi) ? i : ihi;
                int j = d - ic;
                float xb0 = xl[ic * 32 + j];
                float xb1 = xl[1024 + ic * 32 + j];
#pragma unroll
                for (int nt = 0; nt < 2; nt++) {
                    int hh = wn * 32 + nt * 16 + l16;
                    float2 ht2 = *(float2*)&hf[pb][(ic * H_ + hh) * 2];
                    float2 hl2 = *(float2*)&hf[pb][((ic + 1) * H_ + hh) * 2];
#pragma unroll
                    for (int rr = 0; rr < 2; rr++) {
                        int r = p2 * 2 + rr;
                        float xb = rr ? xb1 : xb0;
                        float Gr = acc[mt][0][nt][r];
                        float Gz = acc[mt][1][nt][r];
                        float Gn = acc[mt][2][nt][r];
                        float rg = fsig(xb * wxs[nt][0] + bs[nt][0] + Gr);
                        float zg = fsig(xb * wxs[nt][1] + bs[nt][1] + Gz);
                        float ng = ftanh(xb * wxs[nt][2] + bs[nt][2] + rg * Gn);
                        float hthl = rr ? (ht2.y + hl2.y) : (ht2.x + hl2.x);
                        hreg[mt][nt][r] = (1.0f - zg) * ng + zg * 0.5f * hthl;
                    }
                }
            }
        }
        __syncthreads();
        // write phase: new h -> f32 cur buf + bf16 (swizzled), valid rows only
#pragma unroll
        for (int mt = 0; mt < 4; mt++) {
#pragma unroll
            for (int p2 = 0; p2 < 2; p2++) {
                int ci = mt * 8 + (lg << 1) + p2;
                int i = ilo + ci;
                if (ci < w) {
                    int sl = i + 1;
                    int sx = (sl & 7) << 4;
#pragma unroll
                    for (int nt = 0; nt < 2; nt++) {
                        int hh = wn * 32 + nt * 16 + l16;
                        float h0 = hreg[mt][nt][p2 * 2];
                        float h1 = hreg[mt][nt][p2 * 2 + 1];
                        *(float2*)&hf[cb][(sl * H_ + hh) * 2] = make_float2(h0, h1);
                        int hb = (hh * 2) ^ sx;
                        *(ushort*)((char*)hbf + sl * 512 + hb) = f2bf(h0);
                        *(ushort*)((char*)hbf + sl * 512 + 256 + hb) = f2bf(h1);
                    }
                }
            }
        }
        __syncthreads();
    }

    // terminal corner h (cell 31,31) is hreg[0][*][0..1] on lg==0 lanes
    if (lg == 0) {
#pragma unroll
        for (int nt = 0; nt < 2; nt++) {
            int hh = wn * 32 + nt * 16 + l16;
#pragma unroll
            for (int rr = 0; rr < 2; rr++) {
                int b = chunk * 2 + rr;
                finals[(a * B_ + b) * H_ + hh] = hreg[0][nt][rr];
            }
        }
    }
}

// ---- final: concat 4 terminal h's -> logits -> log_softmax ----
__global__ void classify(const float* __restrict__ fin, const float* __restrict__ Wo,
                         const float* __restrict__ bo, float* __restrict__ out) {
    int b = blockIdx.x;
    int lane = threadIdx.x;  // 64
    float acc[10];
#pragma unroll
    for (int o = 0; o < 10; o++) acc[o] = 0.0f;
#pragma unroll
    for (int kkx = 0; kkx < 8; kkx++) {
        int k = kkx * 64 + lane;
        int a = k >> 7, hh = k & 127;
        float fh = fin[(a * B_ + b) * H_ + hh];
#pragma unroll
        for (int o = 0; o < 10; o++) acc[o] += fh * Wo[k * 10 + o];
    }
    float logits[10];
#pragma unroll
    for (int o = 0; o < 10; o++) {
        float v = acc[o];
#pragma unroll
        for (int off = 32; off; off >>= 1) v += __shfl_xor(v, off, 64);
        logits[o] = v + bo[o];
    }
    float m = logits[0];
#pragma unroll
    for (int o = 1; o < 10; o++) m = fmaxf(m, logits[o]);
    float s = 0.0f;
#pragma unroll
    for (int o = 0; o < 10; o++) s += __expf(logits[o] - m);
    float lse = m + __logf(s);
    if (lane == 0) {
#pragma unroll
        for (int o = 0; o < 10; o++) out[b * 10 + o] = logits[o] - lse;
    }
}

extern "C" void kernel_launch(void* const* d_in, const int* in_sizes, int n_in,
                              void* d_out, int out_size, void* d_ws, size_t ws_size,
                              hipStream_t stream) {
    const float* x = (const float*)d_in[0];
    const float* Wx = (const float*)d_in[1];
    const float* U1 = (const float*)d_in[2];
    const float* U2 = (const float*)d_in[3];
    const float* bv = (const float*)d_in[4];
    const float* Wo = (const float*)d_in[5];
    const float* bo = (const float*)d_in[6];
    float* out = (float*)d_out;

    char* ws = (char*)d_ws;
    ushort* ubf = (ushort*)ws;                    // 786432 B
    float* finals = (float*)(ws + 786432);        // 4*128*128*4 = 256 KB

    hipLaunchKernelGGL(conv_u, dim3(384), dim3(32, 8), 0, stream, U1, U2, ubf);
    hipLaunchKernelGGL(scan_all, dim3(256), dim3(256), 0, stream, x, Wx, bv, ubf, finals);
    hipLaunchKernelGGL(classify, dim3(128), dim3(64), 0, stream, finals, Wo, bo, out);
}

// Round 3
// 311.736 us; speedup vs baseline: 4.4666x; 1.3787x over previous
//
#include <hip/hip_runtime.h>

// MD-GRU (4-direction 2D GRU), block-resident wavefront scan, v3.
// 256 blocks x 512 threads (8 waves). Each block: 1 dir x 2 batch elems,
// entire 63-step diagonal recurrence in LDS. 8 waves split N=384 eight ways.
// Double-buffered h (bf16 swizzled for MFMA A + padded f32 for mix term),
// one barrier per step. Invalid mt tiles skipped (wave-uniform).
// Workspace: [0,786432) U^T bf16 [a][n(384)][kk(256)]; then finals f32 [a][b][hh].

#define B_ 128
#define N_ 32
#define H_ 128
#define TH 384
#define KK 256
#define PADF 264  // f32 h slot stride (128 hh * 2 bl + 8 pad) -> bank shift 8/slot

typedef short bf16x8 __attribute__((ext_vector_type(8)));
typedef float f32x4 __attribute__((ext_vector_type(4)));

__device__ inline ushort f2bf(float f) {
    unsigned u = __float_as_uint(f);
    return (ushort)((u + 0x7FFFu + ((u >> 16) & 1u)) >> 16);  // RNE
}
__device__ inline float fsig(float x) { return 1.0f / (1.0f + __expf(-x)); }
__device__ inline float ftanh2(float x) {  // tanh(x) = 2*sigmoid(2x) - 1
    float e = __expf(-2.0f * x);
    return __builtin_fmaf(2.0f, 1.0f / (1.0f + e), -1.0f);
}

// ---- U1,U2 (f32, [a][k][n]) -> U^T bf16 [a][n][kk], kk = mat*128 + k ----
__global__ void conv_u(const float* __restrict__ U1, const float* __restrict__ U2,
                       ushort* __restrict__ ubf) {
    __shared__ float t[32][33];
    int bx = blockIdx.x;
    int amat = bx / 48, tile = bx % 48;
    int kt = tile / 12, ntl = tile % 12;
    int a = amat >> 1, mat = amat & 1;
    int kk0 = kt * 32, n0 = ntl * 32;
    int tx = threadIdx.x, ty = threadIdx.y;
    const float* U = mat ? U2 : U1;
#pragma unroll
    for (int r = 0; r < 4; r++)
        t[ty + r * 8][tx] = U[(a * H_ + kk0 + ty + r * 8) * TH + n0 + tx];
    __syncthreads();
#pragma unroll
    for (int r = 0; r < 4; r++) {
        int n = n0 + ty + r * 8;
        int kkl = kk0 + tx;
        ubf[(a * TH + n) * KK + mat * H_ + kkl] = f2bf(t[tx][ty + r * 8]);
    }
}

// ---- persistent block-resident scan: 256 blocks x 512 threads (8 waves) ----
__global__ __launch_bounds__(512, 2) void scan_all(
    const float* __restrict__ x, const float* __restrict__ Wx,
    const float* __restrict__ bvec, const ushort* __restrict__ ubf,
    float* __restrict__ finals) {

    __shared__ ushort hbf[2][33 * 256];  // [buf][slot(33)][bl(2)][hh(128)] bf16, XOR-swizzled
    __shared__ float hf[2][33 * PADF];   // [buf][slot(33)][hh(128) x bl(2) + pad] f32
    __shared__ float xl[2 * 1024];       // [bl][i*32+j] pre-flipped

    int bx = blockIdx.x;
    int a = bx >> 6, chunk = bx & 63;
    int tid = threadIdx.x;
    int lane = tid & 63, wn = tid >> 6;  // wn in [0,8): N-split
    int l16 = lane & 15, lg = lane >> 4;

    for (int idx = tid; idx < 2 * 33 * 256; idx += 512) ((ushort*)hbf)[idx] = 0;
    for (int idx = tid; idx < 2 * 33 * PADF; idx += 512) ((float*)hf)[idx] = 0.0f;
    for (int idx = tid; idx < 2048; idx += 512) {
        int bl = idx >> 10, cell = idx & 1023;
        int i = cell >> 5, j = cell & 31;
        int ri = (a & 1) ? (31 - i) : i;
        int cj = (a & 2) ? (31 - j) : j;
        int b = chunk * 2 + bl;
        xl[idx] = x[(b * N_ + ri) * N_ + cj];
    }

    // persistent U^T fragments: per wave 3 p-groups x 16 cols, 24 frags (96 VGPR)
    const ushort* ub = ubf + a * (TH * KK);
    bf16x8 Bf[3][8];
#pragma unroll
    for (int p = 0; p < 3; p++) {
        int n = p * H_ + wn * 16 + l16;
#pragma unroll
        for (int ks = 0; ks < 8; ks++)
            Bf[p][ks] = *(const bf16x8*)(ub + n * KK + ks * 32 + lg * 8);
    }

    int hh = wn * 16 + l16;
    float wxs[3], bs[3];
#pragma unroll
    for (int p = 0; p < 3; p++) {
        wxs[p] = Wx[a * TH + p * H_ + hh];
        bs[p] = bvec[a * TH + p * H_ + hh];
    }
    __syncthreads();

    int ciA = l16 >> 1;  // A-load cell within mt tile
    int blA = l16 & 1;

    for (int d = 0; d < 63; d++) {
        int ilo = (d > 31) ? (d - 31) : 0;
        int ihi = (d < 31) ? d : 31;
        int w = ihi - ilo + 1;
        int nmt = (w + 7) >> 3;
        int wr = d & 1, rd = wr ^ 1;

        // per-mt A-load bases (lane-local clamped slot indexing)
        int tb[4], txr[4], lb[4], lxr[4];
#pragma unroll
        for (int mt = 0; mt < 4; mt++) {
            int ci = mt * 8 + ciA;
            int i = ilo + ci;
            int ic = (i < ihi) ? i : ihi;
            tb[mt] = ic * 512 + blA * 256;
            txr[mt] = (ic & 7) << 4;
            lb[mt] = tb[mt] + 512;
            lxr[mt] = ((ic + 1) & 7) << 4;
        }

        const char* hb = (const char*)&hbf[rd][0];
        f32x4 acc[4][3];
        bf16x8 Af[2][4];
#pragma unroll
        for (int mt = 0; mt < 4; mt++)
            if (mt < nmt)
                Af[0][mt] = *(const bf16x8*)(hb + tb[mt] + ((lg * 16) ^ txr[mt]));
#pragma unroll
        for (int ks = 0; ks < 8; ks++) {
            if (ks < 7) {
                int ks1 = ks + 1;
#pragma unroll
                for (int mt = 0; mt < 4; mt++)
                    if (mt < nmt) {
                        int base = (ks1 < 4) ? tb[mt] : lb[mt];
                        int sx = (ks1 < 4) ? txr[mt] : lxr[mt];
                        int off = base + ((((ks1 & 3) * 64) + lg * 16) ^ sx);
                        Af[ks1 & 1][mt] = *(const bf16x8*)(hb + off);
                    }
            }
#pragma unroll
            for (int p = 0; p < 3; p++)
#pragma unroll
                for (int mt = 0; mt < 4; mt++)
                    if (mt < nmt) {
                        f32x4 cin = (ks == 0) ? (f32x4){0.0f, 0.0f, 0.0f, 0.0f}
                                              : acc[mt][p];
                        acc[mt][p] = __builtin_amdgcn_mfma_f32_16x16x32_bf16(
                            Af[ks & 1][mt], Bf[p][ks], cin, 0, 0, 0);
                    }
        }

        // fused epilogue + write (reads buf rd, writes buf wr)
        char* hbw = (char*)&hbf[wr][0];
#pragma unroll
        for (int mt = 0; mt < 4; mt++) {
            if (mt < nmt) {
#pragma unroll
                for (int p2 = 0; p2 < 2; p2++) {
                    int ci = mt * 8 + lg * 2 + p2;
                    int i = ilo + ci;
                    int ic = (i < ihi) ? i : ihi;
                    int j = d - ic;
                    float xb0 = xl[ic * 32 + j];
                    float xb1 = xl[1024 + ic * 32 + j];
                    float2 ht2 = *(float2*)&hf[rd][ic * PADF + hh * 2];
                    float2 hl2 = *(float2*)&hf[rd][(ic + 1) * PADF + hh * 2];
                    float hv[2];
#pragma unroll
                    for (int rr = 0; rr < 2; rr++) {
                        int r = p2 * 2 + rr;
                        float xb = rr ? xb1 : xb0;
                        float Gr = acc[mt][0][r];
                        float Gz = acc[mt][1][r];
                        float Gn = acc[mt][2][r];
                        float rg = fsig(__builtin_fmaf(xb, wxs[0], bs[0]) + Gr);
                        float zg = fsig(__builtin_fmaf(xb, wxs[1], bs[1]) + Gz);
                        float ng = ftanh2(
                            __builtin_fmaf(rg, Gn, __builtin_fmaf(xb, wxs[2], bs[2])));
                        float hs = rr ? (ht2.y + hl2.y) : (ht2.x + hl2.x);
                        float tmp = __builtin_fmaf(-0.5f, hs, ng);
                        hv[rr] = __builtin_fmaf(-zg, tmp, ng);
                    }
                    if (ci < w) {
                        int sl = i + 1;
                        int sx = (sl & 7) << 4;
                        *(float2*)&hf[wr][sl * PADF + hh * 2] = make_float2(hv[0], hv[1]);
                        int hb2 = (hh * 2) ^ sx;
                        *(ushort*)(hbw + sl * 512 + hb2) = f2bf(hv[0]);
                        *(ushort*)(hbw + sl * 512 + 256 + hb2) = f2bf(hv[1]);
                        if (d == 62) {
                            int b0 = chunk * 2;
                            finals[(a * B_ + b0) * H_ + hh] = hv[0];
                            finals[(a * B_ + b0 + 1) * H_ + hh] = hv[1];
                        }
                    }
                }
            }
        }
        __syncthreads();
    }
}

// ---- final: concat 4 terminal h's -> logits -> log_softmax ----
__global__ void classify(const float* __restrict__ fin, const float* __restrict__ Wo,
                         const float* __restrict__ bo, float* __restrict__ out) {
    int b = blockIdx.x;
    int lane = threadIdx.x;  // 64
    float acc[10];
#pragma unroll
    for (int o = 0; o < 10; o++) acc[o] = 0.0f;
#pragma unroll
    for (int kkx = 0; kkx < 8; kkx++) {
        int k = kkx * 64 + lane;
        int a = k >> 7, hh = k & 127;
        float fh = fin[(a * B_ + b) * H_ + hh];
#pragma unroll
        for (int o = 0; o < 10; o++) acc[o] += fh * Wo[k * 10 + o];
    }
    float logits[10];
#pragma unroll
    for (int o = 0; o < 10; o++) {
        float v = acc[o];
#pragma unroll
        for (int off = 32; off; off >>= 1) v += __shfl_xor(v, off, 64);
        logits[o] = v + bo[o];
    }
    float m = logits[0];
#pragma unroll
    for (int o = 1; o < 10; o++) m = fmaxf(m, logits[o]);
    float s = 0.0f;
#pragma unroll
    for (int o = 0; o < 10; o++) s += __expf(logits[o] - m);
    float lse = m + __logf(s);
    if (lane == 0) {
#pragma unroll
        for (int o = 0; o < 10; o++) out[b * 10 + o] = logits[o] - lse;
    }
}

extern "C" void kernel_launch(void* const* d_in, const int* in_sizes, int n_in,
                              void* d_out, int out_size, void* d_ws, size_t ws_size,
                              hipStream_t stream) {
    const float* x = (const float*)d_in[0];
    const float* Wx = (const float*)d_in[1];
    const float* U1 = (const float*)d_in[2];
    const float* U2 = (const float*)d_in[3];
    const float* bv = (const float*)d_in[4];
    const float* Wo = (const float*)d_in[5];
    const float* bo = (const float*)d_in[6];
    float* out = (float*)d_out;

    char* ws = (char*)d_ws;
    ushort* ubf = (ushort*)ws;                // 786432 B
    float* finals = (float*)(ws + 786432);    // 4*128*128*4 = 256 KB

    hipLaunchKernelGGL(conv_u, dim3(384), dim3(32, 8), 0, stream, U1, U2, ubf);
    hipLaunchKernelGGL(scan_all, dim3(256), dim3(512), 0, stream, x, Wx, bv, ubf, finals);
    hipLaunchKernelGGL(classify, dim3(128), dim3(64), 0, stream, finals, Wo, bo, out);
}